// Round 1
// 1925.078 us; speedup vs baseline: 1.0512x; 1.0512x over previous
//
#include <hip/hip_runtime.h>

// Equivariant graph attention (Transformer_41480794145180) — fp32 throughout.
//
// Pipeline (all on `stream`, no atomics on the hot path):
//   k_zero/k_hist/k_scan/k_fill : build CSR of edges grouped by dst node
//   k_nodeA : per-node A[h,v(,d)] = sum_u W_dot[t,h,u,v] * x_dst[u(,d)]
//             (moves the 32x32 bilinear form out of the edge loop)
//   k_edge1 : per dst-node: k-MLP -> k-terms -> d[e,h] -> expw -> z ->
//             sa = sqrt(relu(alpha)) stored to ws in CSR order
//   k_edge2 : per dst-node: v-MLP -> v-terms * sa -> LDS aggregation ->
//             fused output linear (W_lin_s / W_lin_v) -> d_out
//
// MLP second layer (64->128, the FLOP hot spot) is register-blocked 4 edges
// per wave with weights in a [l/4][j][4] LDS layout so every weight fetch is a
// conflict-free ds_read_b128 shared by 4 edges.
//
// R1 changes (latency-bound per rocprof: VALUBusy 21%, Occ 11%, HBM 1.8%):
//  - NPB=4 nodes per block: weight staging (32KB wq etc.) amortized 4x.
//  - Removed the two per-iteration __syncthreads in the edge loops: Hs is
//    wave-private (written Hs[wave][.][lane], read Hs[wave][.][q*4]); DS ops
//    are in-order within a wave, so no block barrier is required. Waves now
//    run decoupled through the whole edge loop.
//  - esrc/eattr (and sa in pass 2) prefetched at eid-load time so the
//    node_f gather chain is not serialized behind the MLP.

constexpr float INV3    = 0.57735026918962576f;  // 1/sqrt(3)
constexpr float INV_SQ8 = 0.35355339059327373f;  // 1/sqrt(N_BASIS=8)
constexpr float INV_HID = 0.125f;                // 1/sqrt(HID=64)
constexpr float INV_FAN = 0.015625f;             // 1/sqrt(4*32*32)
constexpr float INV_L   = 0.125f;                // 1/sqrt(2*MUL=64)
constexpr int   MAXD    = 256;                   // max in-degree (Poisson(32), max~70)
constexpr int   NPB     = 4;                     // dst nodes per block (edge kernels)

// jax.nn.gelu default (approximate=True, tanh form)
__device__ __forceinline__ float gelu_tanh(float x) {
  float u = 0.7978845608028654f * (x + 0.044715f * x * x * x);
  float e = __expf(2.0f * u);            // e=inf / e=0 limits are exact
  return x * (1.0f - 1.0f / (e + 1.0f)); // = 0.5x(1+tanh(u))
}

// ---------------- CSR build ----------------
__global__ void k_zero(int* __restrict__ p, int n) {
  int i = blockIdx.x * 256 + threadIdx.x;
  if (i < n) p[i] = 0;
}

__global__ void k_hist(const int* __restrict__ dst, int* __restrict__ cnt, int E) {
  int e = blockIdx.x * 256 + threadIdx.x;
  if (e < E) atomicAdd(&cnt[dst[e]], 1);
}

// single-block exclusive scan over N counts -> rowptr[0..N]
__global__ __launch_bounds__(256) void k_scan(const int* __restrict__ cnt,
                                              int* __restrict__ rowptr, int N) {
  __shared__ int wsum[4];
  __shared__ int woff[4];
  __shared__ int carry;
  int t = threadIdx.x, wave = t >> 6, lane = t & 63;
  if (t == 0) { carry = 0; rowptr[0] = 0; }
  __syncthreads();
  for (int base = 0; base < N; base += 256) {
    int i = base + t;
    int inc = (i < N) ? cnt[i] : 0;
#pragma unroll
    for (int off = 1; off < 64; off <<= 1) {
      int y = __shfl_up(inc, off, 64);
      if (lane >= off) inc += y;
    }
    if (lane == 63) wsum[wave] = inc;
    __syncthreads();
    if (t == 0) {
      int r = 0;
      for (int w = 0; w < 4; w++) { woff[w] = r; r += wsum[w]; }
    }
    __syncthreads();
    int incl = inc + woff[wave] + carry;
    if (i < N) rowptr[i + 1] = incl;
    __syncthreads();
    if (t == 255) carry = incl;  // padded lanes add 0, so this is the chunk total
    __syncthreads();
  }
}

__global__ void k_fill(const int* __restrict__ dst, const int* __restrict__ rowptr,
                       int* __restrict__ cursor, int* __restrict__ csr, int E) {
  int e = blockIdx.x * 256 + threadIdx.x;
  if (e < E) {
    int d = dst[e];
    int s = atomicAdd(&cursor[d], 1);
    csr[rowptr[d] + s] = e;
  }
}

// ---------------- per-node A precompute ----------------
// A layout per node (1024 f32): A0[4][32] | A1[4][32] | A2[4][32][3] | A3[4][32][3]
__global__ __launch_bounds__(256) void k_nodeA(const float* __restrict__ node_f,
                                               const float* __restrict__ Wdot,
                                               float* __restrict__ A, int N) {
  __shared__ float Wd[16384];     // 64 KiB: W_dot[4][4][32][32]
  __shared__ float nfs[32 * 128]; // 16 KiB: 32 nodes' features
  int t = threadIdx.x;
  for (int i = t; i < 16384; i += 256) Wd[i] = Wdot[i];
  int n0 = blockIdx.x * 32;
  int nEnd = min(32, N - n0);
  for (int i = t; i < nEnd * 128; i += 256) nfs[i] = node_f[n0 * 128 + i];
  __syncthreads();
  for (int nn = 0; nn < nEnd; ++nn) {
    const float* nf = &nfs[nn * 128];
    float* An = &A[(n0 + nn) * 1024];
#pragma unroll
    for (int k = 0; k < 4; k++) {
      int o = t + k * 256;  // branch below is uniform per k (no divergence)
      float acc = 0.f;
      if (o < 256) {        // A0 / A1 : scalar q
        int term = o >> 7, h = (o >> 5) & 3, v = o & 31;
        const float* W = &Wd[term * 4096 + h * 1024 + v];
#pragma unroll
        for (int u = 0; u < 32; u++) acc += W[u * 32] * nf[u];
      } else {              // A2 / A3 : vector q
        int r = o - 256;
        int term = 2 + r / 384;
        int rr = r % 384;
        int h = rr / 96, q = rr % 96, v = q / 3, d = q - 3 * (q / 3);
        const float* W = &Wd[term * 4096 + h * 1024 + v];
#pragma unroll
        for (int u = 0; u < 32; u++) acc += W[u * 32] * nf[32 + u * 3 + d];
      }
      An[o] = acc;
    }
  }
}

// ---------------- edge pass 1: attention weights ----------------
__global__ __launch_bounds__(256) void k_edge1(
    const int* __restrict__ csr, const int* __restrict__ rowptr,
    const int* __restrict__ esrc,
    const float* __restrict__ xattr,   // E x 8
    const float* __restrict__ eattr,   // E x 4
    const float* __restrict__ cutoff,  // E
    const float* __restrict__ node_f,  // N x 128
    const float* __restrict__ wk1, const float* __restrict__ bk1,
    const float* __restrict__ wk2,
    const float* __restrict__ A,       // N x 1024
    float* __restrict__ sa_out,        // E x 4, CSR slot order
    int N)
{
  __shared__ __align__(16) float w1s[512];
  __shared__ float b1s[64];
  __shared__ __align__(16) float wq[16][128][4];  // wq[l/4][j][l%4] = wk2[l][j]
  __shared__ float Alds[1024];
  __shared__ __align__(16) float Hs[4][4][64];    // [wave][edge][l] — wave-private
  __shared__ float expws[MAXD][4];
  __shared__ float zs[4];

  int t = threadIdx.x;
  int wave = t >> 6, lane = t & 63;
  for (int i = t; i < 512; i += 256) w1s[i] = wk1[i];
  if (t < 64) b1s[t] = bk1[t];
  for (int i = t; i < 8192; i += 256) { int l = i >> 7, j = i & 127; wq[l >> 2][j][l & 3] = wk2[i]; }

  int v = lane & 31;
  bool hi = lane >= 32;

  int n0 = blockIdx.x * NPB;
  int n1 = min(n0 + NPB, N);
  for (int n = n0; n < n1; ++n) {
    // first pass: also covers the weight-staging WAW->RAR; later passes:
    // WAR on Alds/expws/zs vs previous node's readers
    __syncthreads();
    for (int i = t; i < 1024; i += 256) Alds[i] = A[n * 1024 + i];
    __syncthreads();

    int row0 = rowptr[n];
    int deg = min(rowptr[n + 1] - row0, MAXD);
    int iters = (deg + 15) >> 4;  // 16 edges per block-iteration (4 per wave)

    for (int it = 0; it < iters; ++it) {
      int sbase = it * 16 + wave * 4;
      int eid[4]; bool val[4]; float h[4]; int sp[4]; float4 ya[4];
#pragma unroll
      for (int k = 0; k < 4; k++) {
        int s = sbase + k;
        val[k] = s < deg;
        eid[k] = val[k] ? csr[row0 + s] : 0;
        sp[k] = esrc[eid[k]];                       // prefetch src index
        ya[k] = *((const float4*)eattr + eid[k]);   // prefetch edge attr
      }
      // hidden layer: lane computes h_l (l=lane) for 4 edges
#pragma unroll
      for (int k = 0; k < 4; k++) {
        const float4* xp = (const float4*)xattr + eid[k] * 2;
        float4 xa = xp[0], xb = xp[1];
        float acc = xa.x * w1s[lane]       + xa.y * w1s[64 + lane]
                  + xa.z * w1s[128 + lane] + xa.w * w1s[192 + lane]
                  + xb.x * w1s[256 + lane] + xb.y * w1s[320 + lane]
                  + xb.z * w1s[384 + lane] + xb.w * w1s[448 + lane];
        h[k] = gelu_tanh(acc * INV_SQ8 + b1s[lane]);
      }
      // Hs[wave] is private to this wave: in-wave DS ordering suffices,
      // no __syncthreads needed.
#pragma unroll
      for (int k = 0; k < 4; k++) Hs[wave][k][lane] = h[k];
      // 64->128: lane owns outputs j=lane and j=lane+64 for 4 edges
      float a0[4] = {0, 0, 0, 0}, a1[4] = {0, 0, 0, 0};
#pragma unroll
      for (int q = 0; q < 16; q++) {
        float4 wA = *(const float4*)&wq[q][lane][0];
        float4 wB = *(const float4*)&wq[q][lane + 64][0];
#pragma unroll
        for (int k = 0; k < 4; k++) {
          float4 hq = *(const float4*)&Hs[wave][k][q * 4];
          a0[k] += hq.x * wA.x + hq.y * wA.y + hq.z * wA.z + hq.w * wA.w;
          a1[k] += hq.x * wB.x + hq.y * wB.y + hq.z * wB.z + hq.w * wB.w;
        }
      }
      // attention logit d[e,h] and expw
#pragma unroll
      for (int k = 0; k < 4; k++) {
        if (!val[k]) continue;  // wave-uniform: shfl below is safe
        int e = eid[k];
        float ys = ya[k].x, yv0 = ya[k].y, yv1 = ya[k].z, yv2 = ya[k].w;
        const float* nf = &node_f[sp[k] * 128];
        float wj0 = a0[k] * INV_HID, wj1 = a1[k] * INV_HID;
        float p[4];
        if (!hi) {  // lanes 0..31: k0 (w row 0) + kv0 (w row 2)
          float sxs = nf[v];
          float k0 = wj0 * sxs * ys;
          float kb = INV3 * wj1 * sxs;   // kv0_{v,d} = wj1*sxs*yv_d, term scaled INV3
          const float* A2p = &Alds[256 + v * 3];
#pragma unroll
          for (int h2 = 0; h2 < 4; h2++) {
            float t2 = A2p[h2 * 96] * yv0 + A2p[h2 * 96 + 1] * yv1 + A2p[h2 * 96 + 2] * yv2;
            p[h2] = Alds[h2 * 32 + v] * k0 + kb * t2;
          }
        } else {    // lanes 32..63: k1 (w row 1) + kv1 (w row 3)
          float sv0 = nf[32 + v * 3], sv1 = nf[33 + v * 3], sv2 = nf[34 + v * 3];
          float dotv = sv0 * yv0 + sv1 * yv1 + sv2 * yv2;
          float k1 = wj0 * dotv * INV3;
          float kc = INV3 * wj1 * ys;    // kv1_{v,d} = wj1*sxv_d*ys
          const float* A3p = &Alds[640 + v * 3];
#pragma unroll
          for (int h2 = 0; h2 < 4; h2++) {
            float t2 = A3p[h2 * 96] * sv0 + A3p[h2 * 96 + 1] * sv1 + A3p[h2 * 96 + 2] * sv2;
            p[h2] = Alds[128 + h2 * 32 + v] * k1 + kc * t2;
          }
        }
#pragma unroll
        for (int off = 32; off > 0; off >>= 1) {
#pragma unroll
          for (int h2 = 0; h2 < 4; h2++) p[h2] += __shfl_xor(p[h2], off, 64);
        }
        if (lane == 0) {
          float c = cutoff[e];
          int slot = sbase + k;
#pragma unroll
          for (int h2 = 0; h2 < 4; h2++) expws[slot][h2] = c * __expf(p[h2] * INV_FAN);
        }
      }
    }
    __syncthreads();
    // z per head (wave w owns head w), with the z==0 -> 1 guard
    {
      float pz = 0.f;
      for (int s2 = lane; s2 < deg; s2 += 64) pz += expws[s2][wave];
#pragma unroll
      for (int off = 32; off > 0; off >>= 1) pz += __shfl_xor(pz, off, 64);
      if (lane == 0) zs[wave] = (pz == 0.f) ? 1.f : pz;
    }
    __syncthreads();
    for (int i = t; i < deg * 4; i += 256) {
      int slot = i >> 2, hh2 = i & 3;
      float alpha = expws[slot][hh2] / zs[hh2];
      sa_out[(row0 + slot) * 4 + hh2] = sqrtf(fmaxf(alpha, 0.f));
    }
  }
}

// ---------------- edge pass 2: values + aggregation + output linear ----------------
__global__ __launch_bounds__(256) void k_edge2(
    const int* __restrict__ csr, const int* __restrict__ rowptr,
    const int* __restrict__ esrc,
    const float* __restrict__ xattr, const float* __restrict__ eattr,
    const float* __restrict__ node_f,
    const float* __restrict__ wv1, const float* __restrict__ bv1,
    const float* __restrict__ wv2,
    const float* __restrict__ Wls, const float* __restrict__ Wlv,  // 64x32 each
    const float* __restrict__ sa_in,  // E x 4, CSR slot order
    float* __restrict__ out,          // N x 128
    int N)
{
  __shared__ __align__(16) float w1s[512];
  __shared__ float b1s[64];
  __shared__ __align__(16) float wq[16][128][4];
  __shared__ __align__(16) float Hs[4][4][64];    // wave-private
  __shared__ float aggp[4][256];  // per-wave channel partials
  __shared__ float wls[2048];
  __shared__ float wlv[2048];

  int t = threadIdx.x;
  int wave = t >> 6, lane = t & 63;
  for (int i = t; i < 512; i += 256) w1s[i] = wv1[i];
  if (t < 64) b1s[t] = bv1[t];
  for (int i = t; i < 8192; i += 256) { int l = i >> 7, j = i & 127; wq[l >> 2][j][l & 3] = wv2[i]; }
  for (int i = t; i < 2048; i += 256) { wls[i] = Wls[i]; wlv[i] = Wlv[i]; }

  int v = lane & 31;
  bool hi = lane >= 32;
  int hh = v >> 3;  // head of channel v (m = MUL/H = 8)

  int n0 = blockIdx.x * NPB;
  int n1 = min(n0 + NPB, N);
  for (int n = n0; n < n1; ++n) {
    // covers initial staging; afterwards WAR on aggp vs previous node's
    // out-linear readers
    __syncthreads();

    int row0 = rowptr[n];
    int deg = min(rowptr[n + 1] - row0, MAXD);
    int iters = (deg + 15) >> 4;
    float accS = 0.f, acc0 = 0.f, acc1 = 0.f, acc2 = 0.f;

    for (int it = 0; it < iters; ++it) {
      int sbase = it * 16 + wave * 4;
      int eid[4]; bool val[4]; float h[4]; int sp[4]; float4 ya[4]; float sav[4];
#pragma unroll
      for (int k = 0; k < 4; k++) {
        int s = sbase + k;
        val[k] = s < deg;
        eid[k] = val[k] ? csr[row0 + s] : 0;
        sp[k] = esrc[eid[k]];
        ya[k] = *((const float4*)eattr + eid[k]);
        sav[k] = val[k] ? sa_in[(row0 + s) * 4 + hh] : 0.f;
      }
#pragma unroll
      for (int k = 0; k < 4; k++) {
        const float4* xp = (const float4*)xattr + eid[k] * 2;
        float4 xa = xp[0], xb = xp[1];
        float acc = xa.x * w1s[lane]       + xa.y * w1s[64 + lane]
                  + xa.z * w1s[128 + lane] + xa.w * w1s[192 + lane]
                  + xb.x * w1s[256 + lane] + xb.y * w1s[320 + lane]
                  + xb.z * w1s[384 + lane] + xb.w * w1s[448 + lane];
        h[k] = gelu_tanh(acc * INV_SQ8 + b1s[lane]);
      }
#pragma unroll
      for (int k = 0; k < 4; k++) Hs[wave][k][lane] = h[k];
      // no barrier: Hs[wave] is wave-private
      float a0[4] = {0, 0, 0, 0}, a1[4] = {0, 0, 0, 0};
#pragma unroll
      for (int q = 0; q < 16; q++) {
        float4 wA = *(const float4*)&wq[q][lane][0];
        float4 wB = *(const float4*)&wq[q][lane + 64][0];
#pragma unroll
        for (int k = 0; k < 4; k++) {
          float4 hq = *(const float4*)&Hs[wave][k][q * 4];
          a0[k] += hq.x * wA.x + hq.y * wA.y + hq.z * wA.z + hq.w * wA.w;
          a1[k] += hq.x * wB.x + hq.y * wB.y + hq.z * wB.z + hq.w * wB.w;
        }
      }
#pragma unroll
      for (int k = 0; k < 4; k++) {
        if (!val[k]) continue;
        float ys = ya[k].x, yv0 = ya[k].y, yv1 = ya[k].z, yv2 = ya[k].w;
        const float* nf = &node_f[sp[k] * 128];
        float wj0 = a0[k] * INV_HID, wj1 = a1[k] * INV_HID;
        float sav_k = sav[k];
        if (!hi) {  // v0 -> ch v ; vv0 -> ch 64+3v+d
          float sxs = nf[v];
          accS += wj0 * sxs * ys * sav_k;
          float b = wj1 * sxs * sav_k;
          acc0 += b * yv0; acc1 += b * yv1; acc2 += b * yv2;
        } else {    // v1 -> ch 32+v ; vv1 -> ch 160+3v+d
          float sv0 = nf[32 + v * 3], sv1 = nf[33 + v * 3], sv2 = nf[34 + v * 3];
          float dotv = sv0 * yv0 + sv1 * yv1 + sv2 * yv2;
          accS += wj0 * dotv * INV3 * sav_k;
          float c = wj1 * ys * sav_k;
          acc0 += c * sv0; acc1 += c * sv1; acc2 += c * sv2;
        }
      }
    }
    // per-wave partials (each (wave, channel) written by exactly one lane)
    {
      int chS = hi ? 32 + v : v;
      int chV = hi ? 160 + v * 3 : 64 + v * 3;
      aggp[wave][chS] = accS;
      aggp[wave][chV] = acc0; aggp[wave][chV + 1] = acc1; aggp[wave][chV + 2] = acc2;
    }
    __syncthreads();
    aggp[0][t] = aggp[0][t] + aggp[1][t] + aggp[2][t] + aggp[3][t];  // thread t only touches [.][t]
    __syncthreads();
    const float* agg = aggp[0];
    if (t < 128) {
      float o = 0.f;
      if (t < 32) {            // out_s[w=t] = invL * sum_u s_u * Wls[u][w]
#pragma unroll
        for (int u = 0; u < 64; u++) o += agg[u] * wls[u * 32 + t];
        out[n * 128 + t] = o * INV_L;
      } else {                 // out_v[w][d], i = w*3+d
        int i = t - 32, w = i / 3, d = i - 3 * w;
#pragma unroll
        for (int u = 0; u < 64; u++) o += agg[64 + u * 3 + d] * wlv[u * 32 + w];
        out[n * 128 + 32 + i] = o * INV_L;
      }
    }
  }
}

// ---------------- host launcher ----------------
extern "C" void kernel_launch(void* const* d_in, const int* in_sizes, int n_in,
                              void* d_out, int out_size, void* d_ws, size_t ws_size,
                              hipStream_t stream) {
  const int*   esrc   = (const int*)d_in[0];
  const int*   edst   = (const int*)d_in[1];
  const float* xattr  = (const float*)d_in[2];
  const float* eattr  = (const float*)d_in[3];
  const float* cutoff = (const float*)d_in[4];
  const float* node_f = (const float*)d_in[5];
  const float* wk1    = (const float*)d_in[6];
  const float* bk1    = (const float*)d_in[7];
  const float* wk2    = (const float*)d_in[8];
  const float* wv1    = (const float*)d_in[9];
  const float* bv1    = (const float*)d_in[10];
  const float* wv2    = (const float*)d_in[11];
  const float* Wdot   = (const float*)d_in[12];
  const float* Wls    = (const float*)d_in[13];
  const float* Wlv    = (const float*)d_in[14];
  float* out = (float*)d_out;

  int E = in_sizes[0];
  int N = in_sizes[5] / 128;

  // workspace layout (~47.5 MB):
  float* A  = (float*)d_ws;                 // N*1024 f32
  float* sa = A + (size_t)N * 1024;         // E*4 f32
  int* counts = (int*)(sa + (size_t)E * 4); // N
  int* cursor = counts + N;                 // N
  int* rowptr = cursor + N;                 // N+1
  int* csr    = rowptr + (N + 1);           // E

  k_zero<<<(2 * N + 255) / 256, 256, 0, stream>>>(counts, 2 * N);
  k_hist<<<(E + 255) / 256, 256, 0, stream>>>(edst, counts, E);
  k_scan<<<1, 256, 0, stream>>>(counts, rowptr, N);
  k_fill<<<(E + 255) / 256, 256, 0, stream>>>(edst, rowptr, cursor, csr, E);
  k_nodeA<<<(N + 31) / 32, 256, 0, stream>>>(node_f, Wdot, A, N);
  int nb = (N + NPB - 1) / NPB;
  k_edge1<<<nb, 256, 0, stream>>>(csr, rowptr, esrc, xattr, eattr, cutoff, node_f,
                                  wk1, bk1, wk2, A, sa, N);
  k_edge2<<<nb, 256, 0, stream>>>(csr, rowptr, esrc, xattr, eattr, node_f,
                                  wv1, bv1, wv2, Wls, Wlv, sa, out, N);
}